// Round 11
// baseline (412.651 us; speedup 1.0000x reference)
//
#include <hip/hip_runtime.h>

typedef float     v2f __attribute__((ext_vector_type(2)));
typedef _Float16  v2h __attribute__((ext_vector_type(2)));
typedef unsigned int uint;

#define BB 2048
#define TT 1024
#define CC 9
#define HH 36
#define G3 108                    // 3*HH gate rows
#define CSTEPS 32                 // timesteps per x-chunk
#define CF (CSTEPS * CC)          // 288 f32 per chunk (global side)
#define FS 12                     // padded f32 per step in fstage (48 B)
#define GXS 112                   // f32 stride per step in gxbuf
#define NCH (TT / CSTEPS)         // 32 chunks

// Compiler-level ordering fence for same-wave LDS write->read handoffs
// (R7/R8 lesson: TBAA no-alias between differently-typed LDS puns lets the
// scheduler hoist reads above same-step writes -> stale recurrence).
__device__ __forceinline__ void lds_fence() {
    asm volatile("" ::: "memory");
    __builtin_amdgcn_sched_barrier(0);
}

__device__ __forceinline__ void pinh(v2h& v) {
    uint t = __builtin_bit_cast(uint, v);
    asm volatile("" : "+v"(t));
    v = __builtin_bit_cast(v2h, t);
}

// async global->LDS, 4 B per lane (LDS dest = base + lane*4; global src per-lane)
__device__ __forceinline__ void gload4(const float* g, float* l) {
    __builtin_amdgcn_global_load_lds(
        (const __attribute__((address_space(1))) unsigned int*)g,
        (__attribute__((address_space(3))) unsigned int*)l,
        4, 0, 0);
}

// One wave per batch element. Lane l < 54 owns gate-rows (2l, 2l+1) of 108
// (r:0..35, z:36..71, n:72..107).
// Per chunk of 32 steps: (1) parallel PRE-PASS computes the h-independent
// x-parts gx[step][row] for all rows into LDS (f32, off the serial chain;
// its weights are UNPINNED -- used 32x per kernel, not 1024x, so the step
// loop's pinned set shrinks to 38 regs and finally fits under the ~88
// arch-VGPR cap => no AGPR shuttles). (2) serial step loop: 36 fdot2 in 4
// independent chains, ah scatter (b64), combine+activate (lanes<36),
// h broadcast. x is transposed to padded layout on the GLOBAL side of
// global_load_lds (per-lane src offsets; LDS dest must be linear).
__global__ __launch_bounds__(64)
__attribute__((amdgpu_waves_per_eu(2, 2)))
void gru_kernel(
    const float* __restrict__ x,      // (B,T,C)
    const float* __restrict__ w_ih,   // (3H,C)
    const float* __restrict__ w_hh,   // (3H,H)
    const float* __restrict__ b_ih,   // (3H)
    const float* __restrict__ b_hh,   // (3H)
    const float* __restrict__ w_head, // (1,H)
    const float* __restrict__ b_head, // (1)
    float* __restrict__ out)          // (B,1)
{
    const int b = blockIdx.x;
    const int l = threadIdx.x;

    __shared__ __align__(16) float    fstage[CSTEPS * FS];   // 1536 B, padded x
    __shared__ __align__(16) float    gxbuf[CSTEPS * GXS];   // 14336 B, x-parts
    __shared__ __align__(16) float    ahbuf[128];            // h-parts per row (+pad)
    __shared__ __align__(16) _Float16 hbuf[40];              // h broadcast (36+pad)

    // rows owned by this lane (lanes >= 54 clamp; their writes are masked
    // or land in pad)
    const int i0 = (2 * l     < G3) ? 2 * l     : G3 - 1;
    const int i1 = (2 * l + 1 < G3) ? 2 * l + 1 : G3 - 1;

    // ---- step-loop weights: w_hh fp16 (RTE), PINNED ----
    v2h wh0[18], wh1[18];
    float bB0, bB1;               // h-part bias init (n rows: b_hh; r/z: 0)
    {
        const float* p0 = w_hh + (size_t)i0 * HH;
        const float* p1 = w_hh + (size_t)i1 * HH;
#pragma unroll
        for (int k = 0; k < 18; ++k) {
            wh0[k] = (v2h){(_Float16)p0[2*k], (_Float16)p0[2*k+1]};
            wh1[k] = (v2h){(_Float16)p1[2*k], (_Float16)p1[2*k+1]};
        }
        const bool n0 = i0 >= 2 * HH, n1 = i1 >= 2 * HH;
        bB0 = n0 ? b_hh[i0] : 0.f;
        bB1 = n1 ? b_hh[i1] : 0.f;
    }
#pragma unroll
    for (int k = 0; k < 18; ++k) { pinh(wh0[k]); pinh(wh1[k]); }
    asm volatile("" : "+v"(bB0), "+v"(bB1));

    // ---- pre-pass weights: w_ih f32 + x-bias, UNPINNED (used once/chunk) ----
    v2f wx0[4], wx1[4];
    float w80, w81, bA0, bA1;
    {
        const float* q0 = w_ih + (size_t)i0 * CC;
        const float* q1 = w_ih + (size_t)i1 * CC;
#pragma unroll
        for (int p = 0; p < 4; ++p) {
            wx0[p] = (v2f){q0[2*p], q0[2*p+1]};
            wx1[p] = (v2f){q1[2*p], q1[2*p+1]};
        }
        w80 = q0[8];
        w81 = q1[8];
        const bool n0 = i0 >= 2 * HH, n1 = i1 >= 2 * HH;
        bA0 = n0 ? b_ih[i0] : (b_ih[i0] + b_hh[i0]);
        bA1 = n1 ? b_ih[i1] : (b_ih[i1] + b_hh[i1]);
    }

    // ---- per-lane global-side gather offsets: fstage[k*64+l] = x[s*9+q]
    // with s=(k*64+l)/12, q=(k*64+l)%12 (q>=9 -> pad, clamp src to q=8) ----
    int offk[6];
#pragma unroll
    for (int k = 0; k < 6; ++k) {
        int idx = k * 64 + l;
        int s   = idx / 12;
        int q   = idx - 12 * s;
        offk[k] = s * 9 + (q < 9 ? q : 8);
    }

    const float* xg = x + (size_t)b * (TT * CC);

    // prefetch chunk 0 (transposed-padded)
#pragma unroll
    for (int k = 0; k < 6; ++k) gload4(xg + offk[k], &fstage[k * 64]);

    v2h h2[18];
#pragma unroll
    for (int k = 0; k < 18; ++k) h2[k] = (v2h){(_Float16)0.f, (_Float16)0.f};
    float h_own = 0.f;

    for (int c = 0; c < NCH; ++c) {
        asm volatile("s_waitcnt vmcnt(0)" ::: "memory");
        __builtin_amdgcn_sched_barrier(0);

        // ---- PRE-PASS: gx[s][row] for this chunk (h-independent) ----
        for (int s = 0; s < CSTEPS; ++s) {
            float4 xa = *(const float4*)&fstage[s * FS];
            float4 xc = *(const float4*)&fstage[s * FS + 4];
            float  x8 = fstage[s * FS + 8];
            v2f X0 = (v2f){xa.x, xa.y};
            v2f X1 = (v2f){xa.z, xa.w};
            v2f X2 = (v2f){xc.x, xc.y};
            v2f X3 = (v2f){xc.z, xc.w};
            v2f a0 = (v2f){bA0, 0.f};
            v2f a1 = (v2f){bA1, 0.f};
            a0 = __builtin_elementwise_fma(wx0[0], X0, a0);
            a1 = __builtin_elementwise_fma(wx1[0], X0, a1);
            a0 = __builtin_elementwise_fma(wx0[1], X1, a0);
            a1 = __builtin_elementwise_fma(wx1[1], X1, a1);
            a0 = __builtin_elementwise_fma(wx0[2], X2, a0);
            a1 = __builtin_elementwise_fma(wx1[2], X2, a1);
            a0 = __builtin_elementwise_fma(wx0[3], X3, a0);
            a1 = __builtin_elementwise_fma(wx1[3], X3, a1);
            float ax0 = fmaf(w80, x8, a0.x + a0.y);
            float ax1 = fmaf(w81, x8, a1.x + a1.y);
            if (l < 54) *(v2f*)&gxbuf[s * GXS + 2 * l] = (v2f){ax0, ax1};
        }
        lds_fence();   // gxbuf writes -> step-loop reads

        // ---- issue next chunk's gloads (in flight across the 32 steps) ----
        if (c + 1 < NCH) {
            const float* src = xg + (size_t)(c + 1) * CF;
#pragma unroll
            for (int k = 0; k < 6; ++k) gload4(src + offk[k], &fstage[k * 64]);
        }

        // ---- SERIAL step loop ----
        for (int s = 0; s < CSTEPS; ++s) {
            // h-parts: 4 independent fdot2 chains (halved dep latency)
            float a0a = bB0, a1a = bB1, a0b = 0.f, a1b = 0.f;
#pragma unroll
            for (int k = 0; k < 9; ++k) {
                a0a = __builtin_amdgcn_fdot2(wh0[k],     h2[k],     a0a, false);
                a1a = __builtin_amdgcn_fdot2(wh1[k],     h2[k],     a1a, false);
                a0b = __builtin_amdgcn_fdot2(wh0[k + 9], h2[k + 9], a0b, false);
                a1b = __builtin_amdgcn_fdot2(wh1[k + 9], h2[k + 9], a1b, false);
            }
            float ah0 = a0a + a0b;
            float ah1 = a1a + a1b;

            // rows 2l,2l+1 -> ahbuf[2l],ahbuf[2l+1] (lanes>=54 land in pad)
            *(v2f*)&ahbuf[2 * l] = (v2f){ah0, ah1};
            lds_fence();   // ah scatter -> combine reads

            if (l < HH) {
                float gxr = gxbuf[s * GXS + l];
                float gxz = gxbuf[s * GXS + HH + l];
                float gxn = gxbuf[s * GXS + 2 * HH + l];
                float ahr = ahbuf[l];
                float ahz = ahbuf[HH + l];
                float ahn = ahbuf[2 * HH + l];
                float sr = gxr + ahr;
                float sz = gxz + ahz;
                float r = __builtin_amdgcn_rcpf(1.f + __expf(-sr));
                float z = __builtin_amdgcn_rcpf(1.f + __expf(-sz));
                float a = gxn + r * ahn;
                float n = 1.f - 2.f * __builtin_amdgcn_rcpf(__expf(2.f * a) + 1.f);
                h_own = z * (h_own - n) + n;
                hbuf[l] = (_Float16)h_own;   // RTE
            }
            lds_fence();   // hbuf write -> h2 reads

            // h_t to every lane as fp16 pairs (uniform reads)
#pragma unroll
            for (int q = 0; q < 4; ++q) {
                uint4 t4 = ((const uint4*)hbuf)[q];
                h2[4*q+0] = __builtin_bit_cast(v2h, t4.x);
                h2[4*q+1] = __builtin_bit_cast(v2h, t4.y);
                h2[4*q+2] = __builtin_bit_cast(v2h, t4.z);
                h2[4*q+3] = __builtin_bit_cast(v2h, t4.w);
            }
            {
                uint2 t2 = ((const uint2*)hbuf)[8];
                h2[16] = __builtin_bit_cast(v2h, t2.x);
                h2[17] = __builtin_bit_cast(v2h, t2.y);
            }
        }
    }

    // head: out[b] = sum_j h[j] * w_head[j] + b_head
    float whead = (l < HH) ? w_head[l] : 0.f;
    float v = (l < HH) ? h_own * whead : 0.f;
#pragma unroll
    for (int off = 32; off; off >>= 1) v += __shfl_down(v, off);
    if (l == 0) out[b] = v + b_head[0];
}

extern "C" void kernel_launch(void* const* d_in, const int* in_sizes, int n_in,
                              void* d_out, int out_size, void* d_ws, size_t ws_size,
                              hipStream_t stream) {
    const float* x      = (const float*)d_in[0];
    const float* w_ih   = (const float*)d_in[1];
    const float* w_hh   = (const float*)d_in[2];
    const float* b_ih   = (const float*)d_in[3];
    const float* b_hh   = (const float*)d_in[4];
    const float* w_head = (const float*)d_in[5];
    const float* b_head = (const float*)d_in[6];
    float* out = (float*)d_out;

    gru_kernel<<<BB, 64, 0, stream>>>(x, w_ih, w_hh, b_ih, b_hh,
                                      w_head, b_head, out);
}